// Round 15
// baseline (161.803 us; speedup 1.0000x reference)
//
#include <hip/hip_runtime.h>

// G=256, B=4. Parent/ref coords are even -> compressed key k23=(b,x/2,y/2,z/2)
// in 2^23 (1 MB bitmap). Monotone bijection => same sorted-unique order as ref.
#define WORDS_P  (1u << 18)   // 2^23 / 32
#define NBLK2    1024         // 1024 blocks * 256 words = WORDS_P

typedef float f4_native __attribute__((ext_vector_type(4)));

__device__ __forceinline__ unsigned k23_of(int b, int x, int y, int z) {
  return ((unsigned)b << 21) | ((unsigned)(x >> 1) << 14) |
         ((unsigned)(y >> 1) << 7) | (unsigned)(z >> 1);
}

// ---- K1: zero parbm+refbm (2 MB) + lookback state + counters ----
__global__ __launch_bounds__(256) void fill_ws(f4_native* __restrict__ wsz, size_t n4) {
  size_t stride = (size_t)gridDim.x * 256u;
  f4_native z = {0.f, 0.f, 0.f, 0.f};
  for (size_t i = (size_t)blockIdx.x * 256u + threadIdx.x; i < n4; i += stride)
    wsz[i] = z;
}

// ---- K2: bitmap build (atomics only) ----
__global__ __launch_bounds__(256) void build_bm(const int4* __restrict__ coords, int n,
                                                const int4* __restrict__ ref, int nref,
                                                unsigned* __restrict__ parbm,
                                                unsigned* __restrict__ refbm) {
  unsigned tid = blockIdx.x * 256u + threadIdx.x;
  unsigned nthr = gridDim.x * 256u;
  for (unsigned i = tid; i < (unsigned)(n + nref); i += nthr) {
    if (i < (unsigned)n) {
      int4 c = coords[i];                   // (b,x,y,z)
      unsigned k = k23_of(c.x, c.y, c.z, c.w);
      atomicOr(&parbm[k >> 5], 1u << (k & 31));
    } else {
      int4 c = ref[i - (unsigned)n];        // even coords on stride-2 grid
      unsigned k = k23_of(c.x, c.y, c.z, c.w);
      atomicOr(&refbm[k >> 5], 1u << (k & 31));
    }
  }
}

// ---- K3: fused pop+AND+prefix (decoupled lookback) + emit ----
// look[blk] packs [63:62]=flag (1=aggregate, 2=inclusive prefix), [49:25]=P, [24:0]=M.
// All 1024 blocks (256 thr, <=128 VGPR) are co-resident -> lookback spin is safe
// (block 0 never spins; each block publishes its aggregate before its own lookback;
// rocPRIM's device scan uses the same pattern on this hardware).
__global__ __launch_bounds__(256) void scan_emit(const unsigned* __restrict__ parbm,
                                                 unsigned* __restrict__ refbm,  // ->maskbm
                                                 unsigned long long* __restrict__ look,
                                                 unsigned* __restrict__ counter,
                                                 unsigned* __restrict__ maskpre,
                                                 unsigned* __restrict__ clist,
                                                 unsigned* __restrict__ mrow,
                                                 unsigned* __restrict__ rowinfo,
                                                 float4* __restrict__ out_coords,
                                                 float* __restrict__ out_mask) {
  __shared__ unsigned s[256];
  __shared__ unsigned aggP_s, aggM_s, basP_s, basM_s;
  unsigned t = threadIdx.x, blk = blockIdx.x;
  unsigned w = blk * 256u + t;
  unsigned pw = parbm[w];
  unsigned mw = pw & refbm[w];
  refbm[w] = mw;                             // refbm becomes maskbm
  unsigned cp = __popc(pw), cm = __popc(mw);

  s[t] = cp; __syncthreads();
  for (int off = 128; off > 0; off >>= 1) { if (t < (unsigned)off) s[t] += s[t + off]; __syncthreads(); }
  if (t == 0) aggP_s = s[0];
  __syncthreads();
  s[t] = cm; __syncthreads();
  for (int off = 128; off > 0; off >>= 1) { if (t < (unsigned)off) s[t] += s[t + off]; __syncthreads(); }
  if (t == 0) aggM_s = s[0];
  __syncthreads();

  if (t == 0) {
    unsigned aggP = aggP_s, aggM = aggM_s;
    unsigned long long va = (1ULL << 62) | ((unsigned long long)aggP << 25) |
                            (unsigned long long)aggM;
    atomicExch(&look[blk], va);
    unsigned basP = 0, basM = 0;
    int p = (int)blk - 1;
    while (p >= 0) {
      unsigned long long u;
      do { u = atomicAdd(&look[p], 0ULL); } while ((u >> 62) == 0ULL);
      basP += (unsigned)((u >> 25) & 0x1FFFFFFu);
      basM += (unsigned)(u & 0x1FFFFFFu);
      if ((u >> 62) == 2ULL) break;
      p--;
    }
    unsigned long long vi = (2ULL << 62) |
        ((unsigned long long)(basP + aggP) << 25) | (unsigned long long)(basM + aggM);
    atomicExch(&look[blk], vi);
    basP_s = basP; basM_s = basM;
    if (blk == NBLK2 - 1u) {
      counter[0] = basM + aggM;              // M: total masked parents
      counter[1] = basP + aggP;              // P: total parents
    }
  }
  __syncthreads();
  unsigned basP = basP_s, basM = basM_s;

  // in-block exclusive scans
  s[t] = cp; __syncthreads();
  for (int off = 1; off < 256; off <<= 1) {
    unsigned v = (t >= (unsigned)off) ? s[t - off] : 0u;
    __syncthreads(); s[t] += v; __syncthreads();
  }
  unsigned ppre = basP + ((t == 0) ? 0u : s[t - 1]);
  __syncthreads();
  s[t] = cm; __syncthreads();
  for (int off = 1; off < 256; off <<= 1) {
    unsigned v = (t >= (unsigned)off) ? s[t - off] : 0u;
    __syncthreads(); s[t] += v; __syncthreads();
  }
  unsigned mpre = basM + ((t == 0) ? 0u : s[t - 1]);
  maskpre[w] = mpre;
  // zero exactly the clist slots this word's masked parents will use
  for (unsigned k = 0; k < cm * 8u; k++) clist[mpre * 8u + k] = 0u;

  // emit: coords for all parents, exact mask 0/1, mrow + rowinfo
  unsigned r = ppre, j = mpre, bits = pw;
  while (bits) {
    unsigned b = (unsigned)__ffs((int)bits) - 1u;
    bits &= bits - 1u;
    unsigned k = (w << 5) | b;
    float bb = (float)(k >> 21);
    float x = (float)(((k >> 14) & 127u) << 1);
    float y = (float)(((k >> 7) & 127u) << 1);
    float z = (float)((k & 127u) << 1);
    out_coords[r] = make_float4(bb, x, y, z);
    bool masked = (mw >> b) & 1u;
    out_mask[r] = masked ? 1.0f : 0.0f;
    if (masked) { mrow[j] = r; rowinfo[r] = j + 1u; j++; }
    else rowinfo[r] = 0u;
    r++;
  }
}

// ---- K4: input->clist scatter [0,nbN) + tail rows [P,N) ----
__global__ __launch_bounds__(256) void scatter_tail(const int4* __restrict__ coords, int n,
                                                    const unsigned* __restrict__ maskbm,
                                                    const unsigned* __restrict__ maskpre,
                                                    const unsigned* __restrict__ counter,
                                                    unsigned* __restrict__ clist,
                                                    unsigned* __restrict__ rowinfo,
                                                    float4* __restrict__ out_coords,
                                                    float* __restrict__ out_mask,
                                                    int nbN) {
  if ((int)blockIdx.x < nbN) {
    int i = blockIdx.x * 256 + threadIdx.x;
    if (i >= n) return;
    int4 c = coords[i];
    unsigned k = k23_of(c.x, c.y, c.z, c.w);
    unsigned w = k >> 5, b = k & 31u;
    unsigned mw = maskbm[w];
    if ((mw >> b) & 1u) {
      unsigned j = maskpre[w] + __popc(mw & ((1u << b) - 1u));
      unsigned off = (((unsigned)c.y & 1u) << 2) | (((unsigned)c.z & 1u) << 1) |
                     ((unsigned)c.w & 1u);
      clist[j * 8u + off] = (unsigned)i + 1u;  // row + 1 (0 = absent)
    }
    return;
  }
  // tail: rows [P, N): coords=-1, mask=0, rowinfo=0
  unsigned P = counter[1];
  unsigned idx = (blockIdx.x - nbN) * 256u + threadIdx.x;
  unsigned ntail = (unsigned)n - P;
  float4 m1 = make_float4(-1.f, -1.f, -1.f, -1.f);
  for (unsigned i = idx; i < ntail; i += 64u * 256u) {
    out_coords[P + i] = m1;
    out_mask[P + i] = 0.0f;
    rowinfo[P + i] = 0u;
  }
}

// ---- K5: conv + fill fused. Phase A zeros unmasked rows (16B/lane, nontemporal);
//      phase B computes masked rows (W in LDS). Disjoint rows -> no race. ----
__global__ __launch_bounds__(1024, 8) void conv_fill(const float* __restrict__ feats,
                                                     const float* __restrict__ Wg,
                                                     const float* __restrict__ bias,
                                                     const unsigned* __restrict__ clist,
                                                     const unsigned* __restrict__ mrow,
                                                     const unsigned* __restrict__ rowinfo,
                                                     const unsigned* __restrict__ counter,
                                                     int n,
                                                     float* __restrict__ out_feats) {
  __shared__ float lw[16384];                // all of W: 8*32*64 floats = 64 KB
  for (unsigned t = threadIdx.x; t < 4096u; t += 1024u)
    ((float4*)lw)[t] = ((const float4*)Wg)[t];
  __syncthreads();

  unsigned tid = blockIdx.x * 1024u + threadIdx.x;
  unsigned nthr = gridDim.x * 1024u;

  // phase A: zero-fill out_feats rows with rowinfo==0 (16 float4 per row)
  {
    f4_native z = {0.f, 0.f, 0.f, 0.f};
    size_t n4 = (size_t)n * 16u;
    f4_native* of = (f4_native*)out_feats;
    for (size_t i = tid; i < n4; i += nthr) {
      unsigned row = (unsigned)(i >> 4);
      if (rowinfo[row] == 0u) __builtin_nontemporal_store(z, &of[i]);
    }
  }

  // phase B: conv on masked rows
  unsigned lane = threadIdx.x & 63u;
  unsigned wave = blockIdx.x * 16u + (threadIdx.x >> 6);
  unsigned nwaves = gridDim.x * 16u;
  unsigned M = counter[0];
  float bv = bias[lane];
  for (unsigned j = wave; j < M; j += nwaves) {
    unsigned r = mrow[j];                    // uniform load -> broadcast
    uint4 c0 = *(const uint4*)(clist + (size_t)j * 8u);
    uint4 c1 = *(const uint4*)(clist + (size_t)j * 8u + 4u);
    unsigned cs[8] = {c0.x, c0.y, c0.z, c0.w, c1.x, c1.y, c1.z, c1.w};
    float acc = bv;
#pragma unroll
    for (int i = 0; i < 8; i++) {
      unsigned v = (unsigned)__builtin_amdgcn_readfirstlane((int)cs[i]);
      if (v) {                               // wave-uniform branch
        const float* f = feats + (size_t)(v - 1u) * 32u;   // SGPR base -> s_load
        const float* wl = lw + i * 2048 + lane;
#pragma unroll
        for (int k = 0; k < 32; k++) acc = fmaf(f[k], wl[k * 64], acc);
      }
    }
    out_feats[(size_t)r * 64u + lane] = acc;
  }
}

extern "C" void kernel_launch(void* const* d_in, const int* in_sizes, int n_in,
                              void* d_out, int out_size, void* d_ws, size_t ws_size,
                              hipStream_t stream) {
  const float* feats = (const float*)d_in[0];
  const float* W     = (const float*)d_in[1];
  const float* bias  = (const float*)d_in[2];
  const int4*  coords = (const int4*)d_in[3];
  const int4*  ref    = (const int4*)d_in[4];
  int N    = in_sizes[0] / 32;
  int NREF = in_sizes[4] / 4;

  float* out_coords = (float*)d_out;
  float* out_feats  = out_coords + (size_t)N * 4;
  float* out_mask   = out_feats + (size_t)N * 64;

  char* ws = (char*)d_ws;
  unsigned* parbm   = (unsigned*)(ws);                          // 1 MB
  unsigned* refbm   = (unsigned*)(ws + (1u << 20));             // 1 MB (-> maskbm)
  unsigned long long* look = (unsigned long long*)(ws + (2u << 20));  // 8 KB
  unsigned* counter = (unsigned*)(ws + (2u << 20) + 8192);      // 2 u32
  unsigned* clist   = (unsigned*)(ws + (3u << 20));             // 13 MB (M*8 u32 used)
  unsigned* maskpre = (unsigned*)(ws + (16u << 20));            // 1 MB
  unsigned* mrow    = (unsigned*)(ws + (17u << 20));            // 2 MB (M u32 used)
  unsigned* rowinfo = (unsigned*)(ws + (19u << 20));            // 4 MB (N u32)

  int nbN = (N + 255) / 256;

  // K1: zero parbm+refbm+look+counter (2 MB + 16 KB)
  fill_ws<<<128, 256, 0, stream>>>((f4_native*)ws,
                                   ((size_t)(2u << 20) + 16384u) / 16u);
  // K2: bitmaps (atomics only)
  build_bm<<<2048, 256, 0, stream>>>(coords, N, ref, NREF, parbm, refbm);
  // K3: lookback scan + mask AND + prefixes + clist zero + emit
  scan_emit<<<NBLK2, 256, 0, stream>>>(parbm, refbm, look, counter, maskpre, clist,
                                       mrow, rowinfo, (float4*)out_coords, out_mask);
  // K4: input->clist scatter + tail rows
  scatter_tail<<<nbN + 64, 256, 0, stream>>>(coords, N, refbm, maskpre, counter,
                                             clist, rowinfo, (float4*)out_coords,
                                             out_mask, nbN);
  // K5: conv + fill fused
  conv_fill<<<512, 1024, 0, stream>>>(feats, W, bias, clist, mrow, rowinfo, counter,
                                      N, out_feats);
}

// Round 16
// 142.328 us; speedup vs baseline: 1.1368x; 1.1368x over previous
//
#include <hip/hip_runtime.h>

// G=256, B=4. Parent/ref coords are even -> compressed key k23=(b,x/2,y/2,z/2)
// in 2^23 (1 MB bitmap). Monotone bijection => same sorted-unique order as ref.
#define WORDS_P  (1u << 18)   // 2^23 / 32
#define NBLK2    1024         // 1024 blocks * 256 words = WORDS_P

typedef float f4_native __attribute__((ext_vector_type(4)));

__device__ __forceinline__ unsigned k23_of(int b, int x, int y, int z) {
  return ((unsigned)b << 21) | ((unsigned)(x >> 1) << 14) |
         ((unsigned)(y >> 1) << 7) | (unsigned)(z >> 1);
}

// ---- K1: zero parbm+refbm (2 MB) + lookback state + counters ----
__global__ __launch_bounds__(256) void fill_ws(f4_native* __restrict__ wsz, size_t n4) {
  size_t stride = (size_t)gridDim.x * 256u;
  f4_native z = {0.f, 0.f, 0.f, 0.f};
  for (size_t i = (size_t)blockIdx.x * 256u + threadIdx.x; i < n4; i += stride)
    wsz[i] = z;
}

// ---- K2: fused bitmap build (atomics) + 264 MB out feats+mask zero-fill ----
// (R13-proven: the unconditional NT fill hides the ~6 us of atomic work.)
__global__ __launch_bounds__(256) void build_fill(const int4* __restrict__ coords, int n,
                                                  const int4* __restrict__ ref, int nref,
                                                  unsigned* __restrict__ parbm,
                                                  unsigned* __restrict__ refbm,
                                                  f4_native* __restrict__ ofm,
                                                  size_t n4_ofm) {
  unsigned tid = blockIdx.x * 256u + threadIdx.x;
  unsigned nthr = gridDim.x * 256u;
  for (unsigned i = tid; i < (unsigned)(n + nref); i += nthr) {
    if (i < (unsigned)n) {
      int4 c = coords[i];                   // (b,x,y,z)
      unsigned k = k23_of(c.x, c.y, c.z, c.w);
      atomicOr(&parbm[k >> 5], 1u << (k & 31));
    } else {
      int4 c = ref[i - (unsigned)n];        // even coords on stride-2 grid
      unsigned k = k23_of(c.x, c.y, c.z, c.w);
      atomicOr(&refbm[k >> 5], 1u << (k & 31));
    }
  }
  f4_native z = {0.f, 0.f, 0.f, 0.f};
  for (size_t i = tid; i < n4_ofm; i += nthr)
    __builtin_nontemporal_store(z, &ofm[i]);
}

// ---- K3: fused pop+AND+prefix (decoupled lookback) + emit (R15-proven core) ----
// look[blk] packs [63:62]=flag (1=aggregate, 2=inclusive prefix), [49:25]=P, [24:0]=M.
// All 1024 blocks co-resident; block 0 never spins; aggregate published before lookback.
__global__ __launch_bounds__(256) void scan_emit(const unsigned* __restrict__ parbm,
                                                 unsigned* __restrict__ refbm,  // ->maskbm
                                                 unsigned long long* __restrict__ look,
                                                 unsigned* __restrict__ counter,
                                                 unsigned* __restrict__ maskpre,
                                                 unsigned* __restrict__ clist,
                                                 unsigned* __restrict__ mrow,
                                                 float4* __restrict__ out_coords,
                                                 float* __restrict__ out_mask) {
  __shared__ unsigned s[256];
  __shared__ unsigned aggP_s, aggM_s, basP_s, basM_s;
  unsigned t = threadIdx.x, blk = blockIdx.x;
  unsigned w = blk * 256u + t;
  unsigned pw = parbm[w];
  unsigned mw = pw & refbm[w];
  refbm[w] = mw;                             // refbm becomes maskbm
  unsigned cp = __popc(pw), cm = __popc(mw);

  s[t] = cp; __syncthreads();
  for (int off = 128; off > 0; off >>= 1) { if (t < (unsigned)off) s[t] += s[t + off]; __syncthreads(); }
  if (t == 0) aggP_s = s[0];
  __syncthreads();
  s[t] = cm; __syncthreads();
  for (int off = 128; off > 0; off >>= 1) { if (t < (unsigned)off) s[t] += s[t + off]; __syncthreads(); }
  if (t == 0) aggM_s = s[0];
  __syncthreads();

  if (t == 0) {
    unsigned aggP = aggP_s, aggM = aggM_s;
    unsigned long long va = (1ULL << 62) | ((unsigned long long)aggP << 25) |
                            (unsigned long long)aggM;
    atomicExch(&look[blk], va);
    unsigned basP = 0, basM = 0;
    int p = (int)blk - 1;
    while (p >= 0) {
      unsigned long long u;
      do { u = atomicAdd(&look[p], 0ULL); } while ((u >> 62) == 0ULL);
      basP += (unsigned)((u >> 25) & 0x1FFFFFFu);
      basM += (unsigned)(u & 0x1FFFFFFu);
      if ((u >> 62) == 2ULL) break;
      p--;
    }
    unsigned long long vi = (2ULL << 62) |
        ((unsigned long long)(basP + aggP) << 25) | (unsigned long long)(basM + aggM);
    atomicExch(&look[blk], vi);
    basP_s = basP; basM_s = basM;
    if (blk == NBLK2 - 1u) {
      counter[0] = basM + aggM;              // M: total masked parents
      counter[1] = basP + aggP;              // P: total parents
    }
  }
  __syncthreads();
  unsigned basP = basP_s, basM = basM_s;

  // in-block exclusive scans
  s[t] = cp; __syncthreads();
  for (int off = 1; off < 256; off <<= 1) {
    unsigned v = (t >= (unsigned)off) ? s[t - off] : 0u;
    __syncthreads(); s[t] += v; __syncthreads();
  }
  unsigned ppre = basP + ((t == 0) ? 0u : s[t - 1]);
  __syncthreads();
  s[t] = cm; __syncthreads();
  for (int off = 1; off < 256; off <<= 1) {
    unsigned v = (t >= (unsigned)off) ? s[t - off] : 0u;
    __syncthreads(); s[t] += v; __syncthreads();
  }
  unsigned mpre = basM + ((t == 0) ? 0u : s[t - 1]);
  maskpre[w] = mpre;
  // zero exactly the clist slots this word's masked parents will use
  for (unsigned k = 0; k < cm * 8u; k++) clist[mpre * 8u + k] = 0u;

  // emit: coords for all parents; mask=1 for masked only (zeros from build_fill); mrow
  unsigned r = ppre, j = mpre, bits = pw;
  while (bits) {
    unsigned b = (unsigned)__ffs((int)bits) - 1u;
    bits &= bits - 1u;
    unsigned k = (w << 5) | b;
    float bb = (float)(k >> 21);
    float x = (float)(((k >> 14) & 127u) << 1);
    float y = (float)(((k >> 7) & 127u) << 1);
    float z = (float)((k & 127u) << 1);
    out_coords[r] = make_float4(bb, x, y, z);
    if ((mw >> b) & 1u) {
      out_mask[r] = 1.0f;
      mrow[j++] = r;
    }
    r++;
  }
}

// ---- K4: input->clist scatter [0,nbN) + tail rows [P,N) coords=-1 ----
__global__ __launch_bounds__(256) void scatter_tail(const int4* __restrict__ coords, int n,
                                                    const unsigned* __restrict__ maskbm,
                                                    const unsigned* __restrict__ maskpre,
                                                    const unsigned* __restrict__ counter,
                                                    unsigned* __restrict__ clist,
                                                    float4* __restrict__ out_coords,
                                                    int nbN) {
  if ((int)blockIdx.x < nbN) {
    int i = blockIdx.x * 256 + threadIdx.x;
    if (i >= n) return;
    int4 c = coords[i];
    unsigned k = k23_of(c.x, c.y, c.z, c.w);
    unsigned w = k >> 5, b = k & 31u;
    unsigned mw = maskbm[w];
    if ((mw >> b) & 1u) {
      unsigned j = maskpre[w] + __popc(mw & ((1u << b) - 1u));
      unsigned off = (((unsigned)c.y & 1u) << 2) | (((unsigned)c.z & 1u) << 1) |
                     ((unsigned)c.w & 1u);
      clist[j * 8u + off] = (unsigned)i + 1u;  // row + 1 (0 = absent)
    }
    return;
  }
  // tail: rows [P, N) get coords = -1 (mask already 0 from build_fill)
  unsigned P = counter[1];
  unsigned idx = (blockIdx.x - nbN) * 256u + threadIdx.x;
  unsigned ntail = (unsigned)n - P;
  float4 m1 = make_float4(-1.f, -1.f, -1.f, -1.f);
  for (unsigned i = idx; i < ntail; i += 64u * 256u) out_coords[P + i] = m1;
}

// ---- K5: conv (R13-proven): W in LDS; one wave per masked parent ----
__global__ __launch_bounds__(1024, 8) void conv_lds(const float* __restrict__ feats,
                                                    const float* __restrict__ Wg,
                                                    const float* __restrict__ bias,
                                                    const unsigned* __restrict__ clist,
                                                    const unsigned* __restrict__ mrow,
                                                    const unsigned* __restrict__ counter,
                                                    float* __restrict__ out_feats) {
  __shared__ float lw[16384];                // all of W: 8*32*64 floats = 64 KB
  for (unsigned t = threadIdx.x; t < 4096u; t += 1024u)
    ((float4*)lw)[t] = ((const float4*)Wg)[t];
  __syncthreads();

  unsigned lane = threadIdx.x & 63u;
  unsigned wave = blockIdx.x * 16u + (threadIdx.x >> 6);
  unsigned nwaves = gridDim.x * 16u;
  unsigned M = counter[0];
  float bv = bias[lane];
  for (unsigned j = wave; j < M; j += nwaves) {
    unsigned r = mrow[j];                    // uniform load -> broadcast
    uint4 c0 = *(const uint4*)(clist + (size_t)j * 8u);
    uint4 c1 = *(const uint4*)(clist + (size_t)j * 8u + 4u);
    unsigned cs[8] = {c0.x, c0.y, c0.z, c0.w, c1.x, c1.y, c1.z, c1.w};
    float acc = bv;
#pragma unroll
    for (int i = 0; i < 8; i++) {
      unsigned v = (unsigned)__builtin_amdgcn_readfirstlane((int)cs[i]);
      if (v) {                               // wave-uniform branch
        const float* f = feats + (size_t)(v - 1u) * 32u;   // SGPR base -> s_load
        const float* wl = lw + i * 2048 + lane;
#pragma unroll
        for (int k = 0; k < 32; k++) acc = fmaf(f[k], wl[k * 64], acc);
      }
    }
    out_feats[(size_t)r * 64u + lane] = acc;
  }
}

extern "C" void kernel_launch(void* const* d_in, const int* in_sizes, int n_in,
                              void* d_out, int out_size, void* d_ws, size_t ws_size,
                              hipStream_t stream) {
  const float* feats = (const float*)d_in[0];
  const float* W     = (const float*)d_in[1];
  const float* bias  = (const float*)d_in[2];
  const int4*  coords = (const int4*)d_in[3];
  const int4*  ref    = (const int4*)d_in[4];
  int N    = in_sizes[0] / 32;
  int NREF = in_sizes[4] / 4;

  float* out_coords = (float*)d_out;
  float* out_feats  = out_coords + (size_t)N * 4;
  float* out_mask   = out_feats + (size_t)N * 64;

  char* ws = (char*)d_ws;
  unsigned* parbm   = (unsigned*)(ws);                          // 1 MB
  unsigned* refbm   = (unsigned*)(ws + (1u << 20));             // 1 MB (-> maskbm)
  unsigned long long* look = (unsigned long long*)(ws + (2u << 20));  // 8 KB
  unsigned* counter = (unsigned*)(ws + (2u << 20) + 8192);      // 2 u32
  unsigned* clist   = (unsigned*)(ws + (3u << 20));             // 13 MB (M*8 u32 used)
  unsigned* maskpre = (unsigned*)(ws + (16u << 20));            // 1 MB
  unsigned* mrow    = (unsigned*)(ws + (17u << 20));            // 2 MB (M u32 used)

  int nbN = (N + 255) / 256;

  // K1: zero parbm+refbm+look+counter (2 MB + 16 KB)
  fill_ws<<<128, 256, 0, stream>>>((f4_native*)ws,
                                   ((size_t)(2u << 20) + 16384u) / 16u);
  // K2: bitmap build + 264 MB out feats+mask zero-fill (fill hides atomics)
  build_fill<<<2048, 256, 0, stream>>>(coords, N, ref, NREF, parbm, refbm,
                                       (f4_native*)out_feats,
                                       (size_t)N * 65u * 4u / 16u);
  // K3: lookback scan + mask AND + maskpre + clist zero + emit
  scan_emit<<<NBLK2, 256, 0, stream>>>(parbm, refbm, look, counter, maskpre, clist,
                                       mrow, (float4*)out_coords, out_mask);
  // K4: input->clist scatter + tail coords
  scatter_tail<<<nbN + 64, 256, 0, stream>>>(coords, N, refbm, maskpre, counter,
                                             clist, (float4*)out_coords, nbN);
  // K5: conv
  conv_lds<<<512, 1024, 0, stream>>>(feats, W, bias, clist, mrow, counter, out_feats);
}

// Round 18
// 132.832 us; speedup vs baseline: 1.2181x; 1.0715x over previous
//
#include <hip/hip_runtime.h>

// G=256, B=4. Parent/ref coords are even -> compressed key k23=(b,x/2,y/2,z/2)
// in 2^23 (1 MB bitmap). Monotone bijection => same sorted-unique order as ref.
#define WORDS_P  (1u << 18)   // 2^23 / 32
#define NBLK2    1024         // 1024 blocks * 256 words = WORDS_P

typedef float f4_native __attribute__((ext_vector_type(4)));

__device__ __forceinline__ unsigned k23_of(int b, int x, int y, int z) {
  return ((unsigned)b << 21) | ((unsigned)(x >> 1) << 14) |
         ((unsigned)(y >> 1) << 7) | (unsigned)(z >> 1);
}

// grid-stride nontemporal zero of float4 range [lo, hi)
__device__ __forceinline__ void fill_slice(f4_native* __restrict__ of, size_t lo,
                                           size_t hi, unsigned tid, unsigned nthr) {
  f4_native z = {0.f, 0.f, 0.f, 0.f};
  for (size_t i = lo + tid; i < hi; i += nthr)
    __builtin_nontemporal_store(z, &of[i]);
}

// ---- K1: zero parbm+refbm (2 MB) ----
__global__ __launch_bounds__(256) void fill_ws(f4_native* __restrict__ wsz, size_t n4) {
  size_t stride = (size_t)gridDim.x * 256u;
  f4_native z = {0.f, 0.f, 0.f, 0.f};
  for (size_t i = (size_t)blockIdx.x * 256u + threadIdx.x; i < n4; i += stride)
    wsz[i] = z;
}

// ---- K2: bitmap build (atomics) + fill slice [3T/4, T) (includes mask region) ----
__global__ __launch_bounds__(256) void build_fill(const int4* __restrict__ coords, int n,
                                                  const int4* __restrict__ ref, int nref,
                                                  unsigned* __restrict__ parbm,
                                                  unsigned* __restrict__ refbm,
                                                  f4_native* __restrict__ ofm,
                                                  size_t lo, size_t hi) {
  unsigned tid = blockIdx.x * 256u + threadIdx.x;
  unsigned nthr = gridDim.x * 256u;
  for (unsigned i = tid; i < (unsigned)(n + nref); i += nthr) {
    if (i < (unsigned)n) {
      int4 c = coords[i];                   // (b,x,y,z)
      unsigned k = k23_of(c.x, c.y, c.z, c.w);
      atomicOr(&parbm[k >> 5], 1u << (k & 31));
    } else {
      int4 c = ref[i - (unsigned)n];        // even coords on stride-2 grid
      unsigned k = k23_of(c.x, c.y, c.z, c.w);
      atomicOr(&refbm[k >> 5], 1u << (k & 31));
    }
  }
  fill_slice(ofm, lo, hi, tid, nthr);
}

// ---- K3: maskbm = parbm & refbm + block sums + fill slice [T/2, 3T/4) ----
__global__ __launch_bounds__(256) void pop2(const unsigned* __restrict__ parbm,
                                            unsigned* __restrict__ refbm,
                                            unsigned* __restrict__ bsums,
                                            f4_native* __restrict__ ofm,
                                            size_t lo, size_t hi) {
  __shared__ unsigned s[256];
  unsigned t = threadIdx.x;
  unsigned w = blockIdx.x * 256u + t;
  unsigned p = parbm[w];
  unsigned m = p & refbm[w];
  refbm[w] = m;                              // refbm becomes maskbm
  s[t] = __popc(p); __syncthreads();
  for (int off = 128; off > 0; off >>= 1) { if (t < (unsigned)off) s[t] += s[t + off]; __syncthreads(); }
  if (t == 0) bsums[blockIdx.x] = s[0];
  __syncthreads();
  s[t] = __popc(m); __syncthreads();
  for (int off = 128; off > 0; off >>= 1) { if (t < (unsigned)off) s[t] += s[t + off]; __syncthreads(); }
  if (t == 0) bsums[NBLK2 + blockIdx.x] = s[0];

  fill_slice(ofm, lo, hi, blockIdx.x * 256u + t, gridDim.x * 256u);
}

// ---- K4: per-word prefixes (self-scanned bsums) + clist zero + totals
//      + fill slice [T/4, T/2) ----
__global__ __launch_bounds__(256) void prefix2b(const unsigned* __restrict__ parbm,
                                                const unsigned* __restrict__ maskbm,
                                                const unsigned* __restrict__ bsums,
                                                unsigned* __restrict__ parpre,
                                                unsigned* __restrict__ maskpre,
                                                unsigned* __restrict__ clist,
                                                unsigned* __restrict__ counter,
                                                f4_native* __restrict__ ofm,
                                                size_t lo, size_t hi) {
  __shared__ unsigned s[256];
  __shared__ unsigned basP_s, basM_s;
  unsigned t = threadIdx.x, blk = blockIdx.x;
  unsigned accP = 0, accM = 0;
  for (unsigned idx = t; idx < blk; idx += 256u) {
    accP += bsums[idx];
    accM += bsums[NBLK2 + idx];
  }
  s[t] = accP; __syncthreads();
  for (int off = 128; off > 0; off >>= 1) { if (t < (unsigned)off) s[t] += s[t + off]; __syncthreads(); }
  if (t == 0) basP_s = s[0];
  __syncthreads();
  s[t] = accM; __syncthreads();
  for (int off = 128; off > 0; off >>= 1) { if (t < (unsigned)off) s[t] += s[t + off]; __syncthreads(); }
  if (t == 0) basM_s = s[0];
  __syncthreads();
  unsigned basP = basP_s, basM = basM_s;

  unsigned w = blk * 256u + t;
  unsigned pw = parbm[w], mw = maskbm[w];
  unsigned cp = __popc(pw), cm = __popc(mw);
  s[t] = cp; __syncthreads();
  for (int off = 1; off < 256; off <<= 1) {
    unsigned v = (t >= (unsigned)off) ? s[t - off] : 0u;
    __syncthreads(); s[t] += v; __syncthreads();
  }
  unsigned ppre = basP + ((t == 0) ? 0u : s[t - 1]);
  parpre[w] = ppre;
  unsigned plast = basP + s[255];
  __syncthreads();
  s[t] = cm; __syncthreads();
  for (int off = 1; off < 256; off <<= 1) {
    unsigned v = (t >= (unsigned)off) ? s[t - off] : 0u;
    __syncthreads(); s[t] += v; __syncthreads();
  }
  unsigned mpre = basM + ((t == 0) ? 0u : s[t - 1]);
  maskpre[w] = mpre;
  for (unsigned k = 0; k < cm * 8u; k++) clist[mpre * 8u + k] = 0u;
  if (blk == NBLK2 - 1u && t == 255u) {
    counter[0] = basM + s[255];              // M: total masked parents
    counter[1] = plast;                      // P: total parents
  }

  fill_slice(ofm, lo, hi, blk * 256u + t, gridDim.x * 256u);
}

// ---- K5: input->clist scatter [0,nbN) + emit [nbN,nbN+1024) + tail
//      + fill slice [0, T/4) (pure feats; conv writes after this kernel) ----
__global__ __launch_bounds__(256) void scatter_emit(const int4* __restrict__ coords, int n,
                                                    const unsigned* __restrict__ parbm,
                                                    const unsigned* __restrict__ parpre,
                                                    const unsigned* __restrict__ maskbm,
                                                    const unsigned* __restrict__ maskpre,
                                                    const unsigned* __restrict__ counter,
                                                    unsigned* __restrict__ clist,
                                                    unsigned* __restrict__ mrow,
                                                    float4* __restrict__ out_coords,
                                                    float* __restrict__ out_mask,
                                                    f4_native* __restrict__ ofm,
                                                    size_t lo, size_t hi,
                                                    int nbN) {
  unsigned tid = blockIdx.x * 256u + threadIdx.x;
  unsigned nthr = gridDim.x * 256u;
  fill_slice(ofm, lo, hi, tid, nthr);

  if ((int)blockIdx.x < nbN) {
    int i = blockIdx.x * 256 + threadIdx.x;
    if (i >= n) return;
    int4 c = coords[i];
    unsigned k = k23_of(c.x, c.y, c.z, c.w);
    unsigned w = k >> 5, b = k & 31u;
    unsigned mw = maskbm[w];
    if ((mw >> b) & 1u) {
      unsigned j = maskpre[w] + __popc(mw & ((1u << b) - 1u));
      unsigned off = (((unsigned)c.y & 1u) << 2) | (((unsigned)c.z & 1u) << 1) |
                     ((unsigned)c.w & 1u);
      clist[j * 8u + off] = (unsigned)i + 1u;  // row + 1 (0 = absent)
    }
    return;
  }
  if ((int)blockIdx.x < nbN + (int)NBLK2) {
    unsigned w = (blockIdx.x - nbN) * 256u + threadIdx.x;
    unsigned bits = parbm[w];
    if (!bits) return;
    unsigned mb = maskbm[w];
    unsigned r = parpre[w];
    unsigned j = maskpre[w];
    while (bits) {
      unsigned b = (unsigned)__ffs((int)bits) - 1u;
      bits &= bits - 1u;
      unsigned k = (w << 5) | b;
      float bb = (float)(k >> 21);
      float x = (float)(((k >> 14) & 127u) << 1);
      float y = (float)(((k >> 7) & 127u) << 1);
      float z = (float)((k & 127u) << 1);
      out_coords[r] = make_float4(bb, x, y, z);
      if ((mb >> b) & 1u) {
        out_mask[r] = 1.0f;                  // mask zeros laid down in K2's slice
        mrow[j++] = r;
      }
      r++;
    }
    return;
  }
  // tail: rows [P, N) get coords = -1
  unsigned P = counter[1];
  unsigned idx = (blockIdx.x - nbN - NBLK2) * 256u + threadIdx.x;
  unsigned ntail = (unsigned)n - P;
  float4 m1 = make_float4(-1.f, -1.f, -1.f, -1.f);
  for (unsigned i = idx; i < ntail; i += 64u * 256u) out_coords[P + i] = m1;
}

// ---- K6: conv (R13-proven): W in LDS; one wave per masked parent ----
__global__ __launch_bounds__(1024, 8) void conv_lds(const float* __restrict__ feats,
                                                    const float* __restrict__ Wg,
                                                    const float* __restrict__ bias,
                                                    const unsigned* __restrict__ clist,
                                                    const unsigned* __restrict__ mrow,
                                                    const unsigned* __restrict__ counter,
                                                    float* __restrict__ out_feats) {
  __shared__ float lw[16384];                // all of W: 8*32*64 floats = 64 KB
  for (unsigned t = threadIdx.x; t < 4096u; t += 1024u)
    ((float4*)lw)[t] = ((const float4*)Wg)[t];
  __syncthreads();

  unsigned lane = threadIdx.x & 63u;
  unsigned wave = blockIdx.x * 16u + (threadIdx.x >> 6);
  unsigned nwaves = gridDim.x * 16u;
  unsigned M = counter[0];
  float bv = bias[lane];
  for (unsigned j = wave; j < M; j += nwaves) {
    unsigned r = mrow[j];                    // uniform load -> broadcast
    uint4 c0 = *(const uint4*)(clist + (size_t)j * 8u);
    uint4 c1 = *(const uint4*)(clist + (size_t)j * 8u + 4u);
    unsigned cs[8] = {c0.x, c0.y, c0.z, c0.w, c1.x, c1.y, c1.z, c1.w};
    float acc = bv;
#pragma unroll
    for (int i = 0; i < 8; i++) {
      unsigned v = (unsigned)__builtin_amdgcn_readfirstlane((int)cs[i]);
      if (v) {                               // wave-uniform branch
        const float* f = feats + (size_t)(v - 1u) * 32u;   // SGPR base -> s_load
        const float* wl = lw + i * 2048 + lane;
#pragma unroll
        for (int k = 0; k < 32; k++) acc = fmaf(f[k], wl[k * 64], acc);
      }
    }
    out_feats[(size_t)r * 64u + lane] = acc;
  }
}

extern "C" void kernel_launch(void* const* d_in, const int* in_sizes, int n_in,
                              void* d_out, int out_size, void* d_ws, size_t ws_size,
                              hipStream_t stream) {
  const float* feats = (const float*)d_in[0];
  const float* W     = (const float*)d_in[1];
  const float* bias  = (const float*)d_in[2];
  const int4*  coords = (const int4*)d_in[3];
  const int4*  ref    = (const int4*)d_in[4];
  int N    = in_sizes[0] / 32;
  int NREF = in_sizes[4] / 4;

  float* out_coords = (float*)d_out;
  float* out_feats  = out_coords + (size_t)N * 4;
  float* out_mask   = out_feats + (size_t)N * 64;

  char* ws = (char*)d_ws;
  unsigned* parbm   = (unsigned*)(ws);                          // 1 MB
  unsigned* refbm   = (unsigned*)(ws + (1u << 20));             // 1 MB (-> maskbm)
  unsigned* maskbm  = refbm;
  unsigned* clist   = (unsigned*)(ws + (2u << 20));             // 13 MB (M*8 u32 used)
  unsigned* parpre  = (unsigned*)(ws + (15u << 20));            // 1 MB
  unsigned* maskpre = (unsigned*)(ws + (16u << 20));            // 1 MB
  unsigned* mrow    = (unsigned*)(ws + (17u << 20));            // 2 MB (M u32 used)
  unsigned* bsums   = (unsigned*)(ws + (19u << 20));            // 2*1024 u32
  unsigned* counter = (unsigned*)(ws + (19u << 20) + 16384);    // 2 u32

  int nbN = (N + 255) / 256;
  f4_native* ofm = (f4_native*)out_feats;
  size_t T  = (size_t)N * 65u / 4u;          // total float4s in feats+mask region
  size_t T1 = T / 4, T2 = T / 2, T3 = 3 * (T / 4);

  // K1: zero parbm+refbm (2 MB)
  fill_ws<<<64, 256, 0, stream>>>((f4_native*)ws, (size_t)(2u << 20) / 16u);
  // K2: bitmap build + fill [3T/4, T)  (covers the whole mask region)
  build_fill<<<2048, 256, 0, stream>>>(coords, N, ref, NREF, parbm, refbm, ofm, T3, T);
  // K3: popcount block sums + mask AND + fill [T/2, 3T/4)
  pop2<<<NBLK2, 256, 0, stream>>>(parbm, refbm, bsums, ofm, T2, T3);
  // K4: prefixes + clist zero + totals + fill [T/4, T/2)
  prefix2b<<<NBLK2, 256, 0, stream>>>(parbm, maskbm, bsums, parpre, maskpre, clist,
                                      counter, ofm, T1, T2);
  // K5: scatter + emit + tail + fill [0, T/4)
  scatter_emit<<<nbN + NBLK2 + 64, 256, 0, stream>>>(coords, N, parbm, parpre, maskbm,
                                                     maskpre, counter, clist, mrow,
                                                     (float4*)out_coords, out_mask,
                                                     ofm, 0, T1, nbN);
  // K6: conv
  conv_lds<<<512, 1024, 0, stream>>>(feats, W, bias, clist, mrow, counter, out_feats);
}